// Round 10
// baseline (746.425 us; speedup 1.0000x reference)
//
#include <hip/hip_runtime.h>
#include <hip/hip_bf16.h>

// B=256, S=512, D=128, R=2048, H=0.5
#define Bn 256
#define Sn 512
#define Dn 128
#define Rn 2048
#define TB 32
#define NBLK (Sn / TB)   // 16 time-blocks
#define LDX 136          // Xs LDS row stride (bf16)
#define LDPs 1028        // PX LDS row stride (bf16), slice width 1024 + 4
#define RG 1024          // r-slice per workgroup (G=2)

using bf16_t = __hip_bfloat16;
typedef short bf16x8 __attribute__((ext_vector_type(8)));
typedef float f32x4 __attribute__((ext_vector_type(4)));
typedef float f32x2 __attribute__((ext_vector_type(2)));

__device__ __forceinline__ f32x2 clip2(f32x2 v) {
  v = __builtin_elementwise_max(v, (f32x2)(-5.f));
  v = __builtin_elementwise_min(v, (f32x2)(5.f));
  return v;
}

// packed fp32x2 -> bf16x2 (RNE), single instruction: lo=bf16(x), hi=bf16(y).
__device__ __forceinline__ unsigned cvt_pk_bf16(f32x2 v) {
  unsigned r;
  asm("v_cvt_pk_bf16_f32 %0, %1, %2" : "=v"(r) : "v"(v.x), "v"(v.y));
  return r;
}

__global__ __launch_bounds__(256) void k_prep(const float* __restrict__ Wp,
                                              const float* __restrict__ Wr,
                                              bf16_t* __restrict__ Wp_b,
                                              bf16_t* __restrict__ Wr_b,
                                              float* __restrict__ losses) {
  const int i = blockIdx.x * 256 + threadIdx.x;
  Wp_b[i] = __float2bfloat16(Wp[i]);
  Wr_b[i] = __float2bfloat16(Wr[i]);
  if (i == 0) { losses[0] = 0.f; losses[1] = 0.f; }
}

__global__ __launch_bounds__(256) void k_zero(float* __restrict__ preds,
                                              const float* __restrict__ br) {
  const int i = blockIdx.x * 256 + threadIdx.x;
  const f32x4 bv = *(const f32x4*)(br + (i & 31) * 4);
  *((f32x4*)preds + i) = bv;
}

// preds = part0(out) + part1 + bias. NT: single-use streams, keep L2 for weights.
__global__ __launch_bounds__(256) void k_combine(float* __restrict__ out,
                                                 const float* __restrict__ part,
                                                 const float* __restrict__ br) {
  const int i = blockIdx.x * 256 + threadIdx.x;
  const f32x4 bv = *(const f32x4*)(br + (i & 31) * 4);
  const f32x4 a = __builtin_nontemporal_load((const f32x4*)out + i);
  const f32x4 p = __builtin_nontemporal_load((const f32x4*)part + i);
  __builtin_nontemporal_store(a + p + bv, (f32x4*)out + i);
}

// Fused pipeline: 512 WGs. b = bid&255, g = bid>>8.
// R1: input-osc A(blk) [tid<128, plain loads — NT hurt: 2nd-reader misses]
//     || readout D(blk-1) [all waves]
// R2: proj B(blk) -> PX (wave-local cols, weight ring depth 4) -> res/out osc
//     C(blk) on the wave-local slice (cvt_pk bf16 pack, fully unrolled).
// LDS 74.6 KB -> 2 WGs/CU.
template <int SPLIT>
__global__ __launch_bounds__(512, 4) void k_fused(
    const float* __restrict__ inp,
    const float* __restrict__ om_i, const float* __restrict__ ga_i,
    const float* __restrict__ al_i,
    const bf16_t* __restrict__ Wp, const float* __restrict__ bp,
    const float* __restrict__ omr, const float* __restrict__ gar,
    const float* __restrict__ alr,
    const float* __restrict__ omo, const float* __restrict__ gao,
    const float* __restrict__ alo,
    const bf16_t* __restrict__ Wr,
    float* __restrict__ preds, float* __restrict__ part,
    float* __restrict__ losses) {
  __shared__ bf16_t Xs[TB * LDX];
  __shared__ bf16_t PX[TB * LDPs];
  __shared__ float smi[8], smo[8];

  const int tid = threadIdx.x;
  const int b = blockIdx.x & 255, g = blockIdx.x >> 8;
  const int rbase = g * RG;
  const int wv = tid >> 6, lane = tid & 63;
  const int lr = lane & 15, lq = lane >> 4;

  float xi = 0.f, yi = 0.f, pc_in = 0.f;
  float w2i = 0.f, g2i = 0.f, ai = 0.f;
  if (tid < Dn) {
    w2i = om_i[tid] * om_i[tid];
    g2i = 2.f * fabsf(ga_i[tid]);
    ai = al_i[tid];
  }
  const float* inpb = inp + (size_t)b * Sn * Dn;

  const int rl = tid * 2;
  f32x2 xr = (f32x2)0.f, yr = (f32x2)0.f, xo = (f32x2)0.f, yo = (f32x2)0.f;
  f32x2 w2r, g2r, arv, w2o, g2o, aov, bpv;
  {
    f32x2 t;
    t = *(const f32x2*)(omr + rbase + rl); w2r = t * t;
    t = *(const f32x2*)(gar + rbase + rl); g2r = __builtin_elementwise_abs(t) * 2.f;
    arv = *(const f32x2*)(alr + rbase + rl);
    t = *(const f32x2*)(omo + rbase + rl); w2o = t * t;
    t = *(const f32x2*)(gao + rbase + rl); g2o = __builtin_elementwise_abs(t) * 2.f;
    aov = *(const f32x2*)(alo + rbase + rl);
    bpv = *(const f32x2*)(bp + rbase + rl);
  }
  f32x2 pc_out2 = (f32x2)0.f;

  const bf16_t* wp_base = Wp + (size_t)(rbase + wv * 128 + lr) * Dn + lq * 8;
  const int d0 = wv * 16;
  const bf16_t* wr_base = Wr + (size_t)(d0 + lr) * Rn + rbase + lq * 8;
  float* pout = (SPLIT && g) ? part : preds;

  // Phase D: readout GEMM, weight ring depth 8 (named regs, static indices).
  auto phaseD = [&](int tp0) {
    f32x4 acc[2][2] = {{(f32x4)0.f, (f32x4)0.f}, {(f32x4)0.f, (f32x4)0.f}};
    bf16x8 bq0 = *(const bf16x8*)(wr_base + 0);
    bf16x8 bq1 = *(const bf16x8*)(wr_base + 32);
    bf16x8 bq2 = *(const bf16x8*)(wr_base + 64);
    bf16x8 bq3 = *(const bf16x8*)(wr_base + 96);
    bf16x8 bq4 = *(const bf16x8*)(wr_base + 128);
    bf16x8 bq5 = *(const bf16x8*)(wr_base + 160);
    bf16x8 bq6 = *(const bf16x8*)(wr_base + 192);
    bf16x8 bq7 = *(const bf16x8*)(wr_base + 224);
#define DSTEP(BQ, K0, PAR)                                                     \
  {                                                                            \
    bf16x8 a0 = *(const bf16x8*)&PX[(0 + lr) * LDPs + (K0) + lq * 8];          \
    bf16x8 a1 = *(const bf16x8*)&PX[(16 + lr) * LDPs + (K0) + lq * 8];         \
    acc[0][PAR] =                                                              \
        __builtin_amdgcn_mfma_f32_16x16x32_bf16(a0, BQ, acc[0][PAR], 0, 0, 0); \
    acc[1][PAR] =                                                              \
        __builtin_amdgcn_mfma_f32_16x16x32_bf16(a1, BQ, acc[1][PAR], 0, 0, 0); \
    if ((K0) + 256 < RG) BQ = *(const bf16x8*)(wr_base + (K0) + 256);          \
  }
    for (int k0 = 0; k0 < RG; k0 += 256) {
      DSTEP(bq0, k0 + 0, 0)
      DSTEP(bq1, k0 + 32, 1)
      DSTEP(bq2, k0 + 64, 0)
      DSTEP(bq3, k0 + 96, 1)
      DSTEP(bq4, k0 + 128, 0)
      DSTEP(bq5, k0 + 160, 1)
      DSTEP(bq6, k0 + 192, 0)
      DSTEP(bq7, k0 + 224, 1)
    }
#undef DSTEP
    float* outb = pout + (size_t)b * Sn * Dn + (size_t)tp0 * Dn;
#pragma unroll
    for (int i = 0; i < 2; ++i) {
      f32x4 s = acc[i][0] + acc[i][1];
#pragma unroll
      for (int r = 0; r < 4; ++r) {
        const int row = i * 16 + lq * 4 + r;
        if (SPLIT)
          __builtin_nontemporal_store(s[r], outb + (size_t)row * Dn + d0 + lr);
        else
          atomicAdd(outb + (size_t)row * Dn + d0 + lr, s[r]);
      }
    }
  };

  for (int blk = 0; blk < NBLK; ++blk) {
    const int t0 = blk * TB;

    // ---- R1: input oscillator A(blk) [plain loads] + D(blk-1) ----
    if (tid < Dn) {
#pragma unroll
      for (int tt = 0; tt < TB; ++tt) {
        const float f = inpb[(size_t)(t0 + tt) * Dn + tid];
        if (t0 + tt > 0) { const float e = xi - f; pc_in += e * e; }
        const float accel = ai * f - g2i * yi - w2i * xi;
        const float xn = fminf(fmaxf(xi + 0.5f * yi, -5.f), 5.f);
        const float yn = fminf(fmaxf(yi + 0.5f * accel, -5.f), 5.f);
        Xs[tt * LDX + tid] = __float2bfloat16(xn);
        xi = xn; yi = yn;
      }
    }
    if (blk > 0) phaseD(t0 - TB);
    __syncthreads();  // Xs ready for B; PX free (D done reading)

    // ---- R2a: proj B(blk): PX[32 x 1024] = Xs[32x128] @ Wp_slice^T ----
    // Weight ring depth 4 (j-tiles), static indices via full unroll.
    {
      bf16x8 af[2][4];
#pragma unroll
      for (int i = 0; i < 2; ++i)
#pragma unroll
        for (int k = 0; k < 4; ++k)
          af[i][k] = *(const bf16x8*)&Xs[(i * 16 + lr) * LDX + k * 32 + lq * 8];

      bf16x8 bfr[4][4];
#pragma unroll
      for (int jj = 0; jj < 4; ++jj)
#pragma unroll
        for (int k = 0; k < 4; ++k)
          bfr[jj][k] = *(const bf16x8*)(wp_base + (size_t)jj * 16 * Dn + k * 32);
#pragma unroll
      for (int j = 0; j < 8; ++j) {
        const int pb = j & 3;
        f32x4 acc[2] = {(f32x4)0.f, (f32x4)0.f};
#pragma unroll
        for (int k = 0; k < 4; ++k) {
          acc[0] = __builtin_amdgcn_mfma_f32_16x16x32_bf16(af[0][k], bfr[pb][k], acc[0], 0, 0, 0);
          acc[1] = __builtin_amdgcn_mfma_f32_16x16x32_bf16(af[1][k], bfr[pb][k], acc[1], 0, 0, 0);
        }
        if (j + 4 < 8) {
#pragma unroll
          for (int k = 0; k < 4; ++k)
            bfr[pb][k] = *(const bf16x8*)(wp_base + (size_t)(j + 4) * 16 * Dn + k * 32);
        }
        const int cl = wv * 128 + j * 16 + lr;
#pragma unroll
        for (int i = 0; i < 2; ++i)
#pragma unroll
          for (int r = 0; r < 4; ++r)
            PX[(i * 16 + lq * 4 + r) * LDPs + cl] = __float2bfloat16(acc[i][r]);
      }
    }

    // ---- R2b: res/out oscillators C(blk), wave-local slice of PX ----
    // (no barrier: this wave wrote PX cols [wv*128, wv*128+128) above)
    {
      unsigned pk = *(unsigned*)&PX[0 * LDPs + rl];
#pragma unroll
      for (int tt = 0; tt < TB; ++tt) {
        unsigned pk_n = pk;
        if (tt + 1 < TB) pk_n = *(unsigned*)&PX[(tt + 1) * LDPs + rl];
        f32x2 pv;
        pv.x = __uint_as_float(pk << 16);
        pv.y = __uint_as_float(pk & 0xffff0000u);
        pv += bpv;
        f32x2 acr = arv * pv - g2r * yr - w2r * xr;
        f32x2 xrn = clip2(xr + yr * 0.5f);
        f32x2 yrn = clip2(yr + acr * 0.5f);
        f32x2 aco = aov * xrn - g2o * yo - w2o * xo;
        f32x2 xon = clip2(xo + yo * 0.5f);
        f32x2 yon = clip2(yo + aco * 0.5f);
        f32x2 e = xon - xrn;
        pc_out2 += e * e;
        xr = xrn; yr = yrn; xo = xon; yo = yon;
        *(unsigned*)&PX[tt * LDPs + rl] = cvt_pk_bf16(xon);
        pk = pk_n;
      }
    }
    __syncthreads();  // x_out slice ready for next R1's D
  }

  phaseD(Sn - TB);

  float vi = pc_in;
  float vo = pc_out2.x + pc_out2.y;
#pragma unroll
  for (int o = 32; o > 0; o >>= 1) {
    vi += __shfl_down(vi, o, 64);
    vo += __shfl_down(vo, o, 64);
  }
  if (lane == 0) { smi[wv] = vi; smo[wv] = vo; }
  __syncthreads();
  if (tid == 0) {
    float si = 0.f, so = 0.f;
#pragma unroll
    for (int w = 0; w < 8; ++w) { si += smi[w]; so += smo[w]; }
    if (g == 0) atomicAdd(losses + 0, si * (1.f / ((float)Bn * (float)Dn)));
    atomicAdd(losses + 1, so * (1.f / ((float)Bn * (float)Rn)));
  }
}

extern "C" void kernel_launch(void* const* d_in, const int* in_sizes, int n_in,
                              void* d_out, int out_size, void* d_ws, size_t ws_size,
                              hipStream_t stream) {
  const float* inputs    = (const float*)d_in[0];
  const float* omega_in  = (const float*)d_in[1];
  const float* gamma_in  = (const float*)d_in[2];
  const float* alpha_in  = (const float*)d_in[3];
  const float* W_proj    = (const float*)d_in[4];
  const float* b_proj    = (const float*)d_in[5];
  const float* omega_res = (const float*)d_in[6];
  const float* gamma_res = (const float*)d_in[7];
  const float* alpha_res = (const float*)d_in[8];
  const float* omega_out = (const float*)d_in[9];
  const float* gamma_out = (const float*)d_in[10];
  const float* alpha_out = (const float*)d_in[11];
  const float* W_read    = (const float*)d_in[12];
  const float* b_read    = (const float*)d_in[13];

  float* out = (float*)d_out;
  float* losses = out + (size_t)Bn * Sn * Dn;  // outputs: preds | pc_in | pc_out

  // ws layout: [Wp_b 512KB][Wr_b 512KB][partial preds 64MB (split mode)]
  bf16_t* Wp_b = (bf16_t*)d_ws;
  bf16_t* Wr_b = Wp_b + (size_t)Rn * Dn;
  float* part = (float*)(Wr_b + (size_t)Rn * Dn);

  const size_t need = 2u * Rn * Dn * sizeof(bf16_t) +
                      (size_t)Bn * Sn * Dn * sizeof(float);
  const bool split = ws_size >= need;

  k_prep<<<1024, 256, 0, stream>>>(W_proj, W_read, Wp_b, Wr_b, losses);
  if (split) {
    k_fused<1><<<Bn * 2, 512, 0, stream>>>(inputs, omega_in, gamma_in, alpha_in,
                                           Wp_b, b_proj,
                                           omega_res, gamma_res, alpha_res,
                                           omega_out, gamma_out, alpha_out,
                                           Wr_b, out, part, losses);
    k_combine<<<(Bn * Sn * Dn / 4) / 256, 256, 0, stream>>>(out, part, b_read);
  } else {
    k_zero<<<(Bn * Sn * Dn / 4) / 256, 256, 0, stream>>>(out, b_read);
    k_fused<0><<<Bn * 2, 512, 0, stream>>>(inputs, omega_in, gamma_in, alpha_in,
                                           Wp_b, b_proj,
                                           omega_res, gamma_res, alpha_res,
                                           omega_out, gamma_out, alpha_out,
                                           Wr_b, out, part, losses);
  }
}

// Round 12
// 716.481 us; speedup vs baseline: 1.0418x; 1.0418x over previous
//
#include <hip/hip_runtime.h>
#include <hip/hip_bf16.h>

// B=256, S=512, D=128, R=2048, H=0.5
#define Bn 256
#define Sn 512
#define Dn 128
#define Rn 2048
#define TB 32
#define NBLK (Sn / TB)   // 16 time-blocks
#define LDX 136          // Xs LDS row stride (bf16)
#define LDPs 1028        // PX LDS row stride (bf16), slice width 1024 + 4
#define RG 1024          // r-slice per workgroup (G=2)

using bf16_t = __hip_bfloat16;
typedef short bf16x8 __attribute__((ext_vector_type(8)));
typedef float f32x4 __attribute__((ext_vector_type(4)));
typedef float f32x2 __attribute__((ext_vector_type(2)));

__device__ __forceinline__ f32x2 clip2(f32x2 v) {
  v = __builtin_elementwise_max(v, (f32x2)(-5.f));
  v = __builtin_elementwise_min(v, (f32x2)(5.f));
  return v;
}

// fp32 -> bf16 bits, round-to-nearest-even (values finite/clamped here).
__device__ __forceinline__ unsigned bf16rne(float f) {
  const unsigned u = __float_as_uint(f);
  return (u + 0x7fffu + ((u >> 16) & 1u)) >> 16;
}
__device__ __forceinline__ unsigned pack_bf16(f32x2 v) {
  return (bf16rne(v.y) << 16) | (bf16rne(v.x) & 0xffffu);
}

__global__ __launch_bounds__(256) void k_prep(const float* __restrict__ Wp,
                                              const float* __restrict__ Wr,
                                              bf16_t* __restrict__ Wp_b,
                                              bf16_t* __restrict__ Wr_b,
                                              float* __restrict__ losses) {
  const int i = blockIdx.x * 256 + threadIdx.x;
  Wp_b[i] = __float2bfloat16(Wp[i]);
  Wr_b[i] = __float2bfloat16(Wr[i]);
  if (i == 0) { losses[0] = 0.f; losses[1] = 0.f; }
}

__global__ __launch_bounds__(256) void k_zero(float* __restrict__ preds,
                                              const float* __restrict__ br) {
  const int i = blockIdx.x * 256 + threadIdx.x;
  const f32x4 bv = *(const f32x4*)(br + (i & 31) * 4);
  *((f32x4*)preds + i) = bv;
}

// preds = part0(out) + part1 + bias. NT: single-use streams, keep L2/L3 for weights.
__global__ __launch_bounds__(256) void k_combine(float* __restrict__ out,
                                                 const float* __restrict__ part,
                                                 const float* __restrict__ br) {
  const int i = blockIdx.x * 256 + threadIdx.x;
  const f32x4 bv = *(const f32x4*)(br + (i & 31) * 4);
  const f32x4 a = __builtin_nontemporal_load((const f32x4*)out + i);
  const f32x4 p = __builtin_nontemporal_load((const f32x4*)part + i);
  __builtin_nontemporal_store(a + p + bv, (f32x4*)out + i);
}

// Fused pipeline: 512 WGs.
// *** XCD weight partition (round-11/12 experiment): b = bid>>1, g = bid&1. ***
// HW round-robins XCD = bid % 8, so even XCDs host only g=0 WGs, odd XCDs only
// g=1 -> per-XCD weight working set = 512 KB (was 1 MB), L2-resident under the
// input/preds stream. Input pair (g0,g1) lands on adjacent XCDs; the second
// reader hits L3.
// R1: input-osc A(blk) [tid<128] || readout D(blk-1) [all waves]
// R2: proj B(blk) -> PX (wave-local cols) -> res/out osc C(blk), no barrier
//     between B and C (wave-local slice). LDS 74.6 KB -> 2 WGs/CU.
template <int SPLIT>
__global__ __launch_bounds__(512, 4) void k_fused(
    const float* __restrict__ inp,
    const float* __restrict__ om_i, const float* __restrict__ ga_i,
    const float* __restrict__ al_i,
    const bf16_t* __restrict__ Wp, const float* __restrict__ bp,
    const float* __restrict__ omr, const float* __restrict__ gar,
    const float* __restrict__ alr,
    const float* __restrict__ omo, const float* __restrict__ gao,
    const float* __restrict__ alo,
    const bf16_t* __restrict__ Wr,
    float* __restrict__ preds, float* __restrict__ part,
    float* __restrict__ losses) {
  __shared__ bf16_t Xs[TB * LDX];
  __shared__ bf16_t PX[TB * LDPs];
  __shared__ float smi[8], smo[8];

  const int tid = threadIdx.x;
  const int b = blockIdx.x >> 1, g = blockIdx.x & 1;  // XCD weight partition
  const int rbase = g * RG;
  const int wv = tid >> 6, lane = tid & 63;
  const int lr = lane & 15, lq = lane >> 4;

  float xi = 0.f, yi = 0.f, pc_in = 0.f;
  float w2i = 0.f, g2i = 0.f, ai = 0.f;
  if (tid < Dn) {
    w2i = om_i[tid] * om_i[tid];
    g2i = 2.f * fabsf(ga_i[tid]);
    ai = al_i[tid];
  }
  const float* inpb = inp + (size_t)b * Sn * Dn;

  const int rl = tid * 2;
  f32x2 xr = (f32x2)0.f, yr = (f32x2)0.f, xo = (f32x2)0.f, yo = (f32x2)0.f;
  f32x2 w2r, g2r, arv, w2o, g2o, aov, bpv;
  {
    f32x2 t;
    t = *(const f32x2*)(omr + rbase + rl); w2r = t * t;
    t = *(const f32x2*)(gar + rbase + rl); g2r = __builtin_elementwise_abs(t) * 2.f;
    arv = *(const f32x2*)(alr + rbase + rl);
    t = *(const f32x2*)(omo + rbase + rl); w2o = t * t;
    t = *(const f32x2*)(gao + rbase + rl); g2o = __builtin_elementwise_abs(t) * 2.f;
    aov = *(const f32x2*)(alo + rbase + rl);
    bpv = *(const f32x2*)(bp + rbase + rl);
  }
  f32x2 pc_out2 = (f32x2)0.f;

  const bf16_t* wp_base = Wp + (size_t)(rbase + wv * 128 + lr) * Dn + lq * 8;
  const int d0 = wv * 16;
  const bf16_t* wr_base = Wr + (size_t)(d0 + lr) * Rn + rbase + lq * 8;
  float* pout = (SPLIT && g) ? part : preds;

  // Phase D: readout GEMM, weight ring depth 4 (r8-proven config).
  auto phaseD = [&](int tp0) {
    f32x4 acc[2][2] = {{(f32x4)0.f, (f32x4)0.f}, {(f32x4)0.f, (f32x4)0.f}};
    bf16x8 bq0 = *(const bf16x8*)(wr_base + 0);
    bf16x8 bq1 = *(const bf16x8*)(wr_base + 32);
    bf16x8 bq2 = *(const bf16x8*)(wr_base + 64);
    bf16x8 bq3 = *(const bf16x8*)(wr_base + 96);
#define DSTEP(BQ, K0, PAR)                                                     \
  {                                                                            \
    bf16x8 a0 = *(const bf16x8*)&PX[(0 + lr) * LDPs + (K0) + lq * 8];          \
    bf16x8 a1 = *(const bf16x8*)&PX[(16 + lr) * LDPs + (K0) + lq * 8];         \
    acc[0][PAR] =                                                              \
        __builtin_amdgcn_mfma_f32_16x16x32_bf16(a0, BQ, acc[0][PAR], 0, 0, 0); \
    acc[1][PAR] =                                                              \
        __builtin_amdgcn_mfma_f32_16x16x32_bf16(a1, BQ, acc[1][PAR], 0, 0, 0); \
    if ((K0) + 128 < RG) BQ = *(const bf16x8*)(wr_base + (K0) + 128);          \
  }
    for (int k0 = 0; k0 < RG; k0 += 128) {
      DSTEP(bq0, k0 + 0, 0)
      DSTEP(bq1, k0 + 32, 1)
      DSTEP(bq2, k0 + 64, 0)
      DSTEP(bq3, k0 + 96, 1)
    }
#undef DSTEP
    float* outb = pout + (size_t)b * Sn * Dn + (size_t)tp0 * Dn;
#pragma unroll
    for (int i = 0; i < 2; ++i) {
      f32x4 s = acc[i][0] + acc[i][1];
#pragma unroll
      for (int r = 0; r < 4; ++r) {
        const int row = i * 16 + lq * 4 + r;
        if (SPLIT)
          __builtin_nontemporal_store(s[r], outb + (size_t)row * Dn + d0 + lr);
        else
          atomicAdd(outb + (size_t)row * Dn + d0 + lr, s[r]);
      }
    }
  };

  for (int blk = 0; blk < NBLK; ++blk) {
    const int t0 = blk * TB;

    // ---- R1: input oscillator A(blk) + D(blk-1) ----
    if (tid < Dn) {
#pragma unroll
      for (int tt = 0; tt < TB; ++tt) {
        const float f = inpb[(size_t)(t0 + tt) * Dn + tid];
        if (t0 + tt > 0) { const float e = xi - f; pc_in += e * e; }
        const float accel = ai * f - g2i * yi - w2i * xi;
        const float xn = fminf(fmaxf(xi + 0.5f * yi, -5.f), 5.f);
        const float yn = fminf(fmaxf(yi + 0.5f * accel, -5.f), 5.f);
        Xs[tt * LDX + tid] = __float2bfloat16(xn);
        xi = xn; yi = yn;
      }
    }
    if (blk > 0) phaseD(t0 - TB);
    __syncthreads();  // Xs ready for B; PX free (D done reading)

    // ---- R2a: proj B(blk): PX[32 x 1024] = Xs[32x128] @ Wp_slice^T ----
    {
      bf16x8 af[2][4];
#pragma unroll
      for (int i = 0; i < 2; ++i)
#pragma unroll
        for (int k = 0; k < 4; ++k)
          af[i][k] = *(const bf16x8*)&Xs[(i * 16 + lr) * LDX + k * 32 + lq * 8];

      bf16x8 bfr[2][4];
#pragma unroll
      for (int k = 0; k < 4; ++k) {
        bfr[0][k] = *(const bf16x8*)(wp_base + (size_t)0 * 16 * Dn + k * 32);
        bfr[1][k] = *(const bf16x8*)(wp_base + (size_t)1 * 16 * Dn + k * 32);
      }
      for (int j = 0; j < 8; ++j) {
        const int pb = j & 1;
        f32x4 acc[2] = {(f32x4)0.f, (f32x4)0.f};
#pragma unroll
        for (int k = 0; k < 4; ++k) {
          acc[0] = __builtin_amdgcn_mfma_f32_16x16x32_bf16(af[0][k], bfr[pb][k], acc[0], 0, 0, 0);
          acc[1] = __builtin_amdgcn_mfma_f32_16x16x32_bf16(af[1][k], bfr[pb][k], acc[1], 0, 0, 0);
        }
        if (j + 2 < 8) {
#pragma unroll
          for (int k = 0; k < 4; ++k)
            bfr[pb][k] = *(const bf16x8*)(wp_base + (size_t)(j + 2) * 16 * Dn + k * 32);
        }
        const int cl = wv * 128 + j * 16 + lr;
#pragma unroll
        for (int i = 0; i < 2; ++i)
#pragma unroll
          for (int r = 0; r < 4; ++r)
            PX[(i * 16 + lq * 4 + r) * LDPs + cl] = __float2bfloat16(acc[i][r]);
      }
    }

    // ---- R2b: res/out oscillators C(blk), wave-local slice of PX ----
    {
      unsigned pk = *(unsigned*)&PX[0 * LDPs + rl];
      for (int tt = 0; tt < TB; ++tt) {
        unsigned pk_n = pk;
        if (tt + 1 < TB) pk_n = *(unsigned*)&PX[(tt + 1) * LDPs + rl];
        f32x2 pv;
        pv.x = __uint_as_float(pk << 16);
        pv.y = __uint_as_float(pk & 0xffff0000u);
        pv += bpv;
        f32x2 acr = arv * pv - g2r * yr - w2r * xr;
        f32x2 xrn = clip2(xr + yr * 0.5f);
        f32x2 yrn = clip2(yr + acr * 0.5f);
        f32x2 aco = aov * xrn - g2o * yo - w2o * xo;
        f32x2 xon = clip2(xo + yo * 0.5f);
        f32x2 yon = clip2(yo + aco * 0.5f);
        f32x2 e = xon - xrn;
        pc_out2 += e * e;
        xr = xrn; yr = yrn; xo = xon; yo = yon;
        *(unsigned*)&PX[tt * LDPs + rl] = pack_bf16(xon);
        pk = pk_n;
      }
    }
    __syncthreads();  // x_out slice ready for next R1's D
  }

  phaseD(Sn - TB);

  float vi = pc_in;
  float vo = pc_out2.x + pc_out2.y;
#pragma unroll
  for (int o = 32; o > 0; o >>= 1) {
    vi += __shfl_down(vi, o, 64);
    vo += __shfl_down(vo, o, 64);
  }
  if (lane == 0) { smi[wv] = vi; smo[wv] = vo; }
  __syncthreads();
  if (tid == 0) {
    float si = 0.f, so = 0.f;
#pragma unroll
    for (int w = 0; w < 8; ++w) { si += smi[w]; so += smo[w]; }
    if (g == 0) atomicAdd(losses + 0, si * (1.f / ((float)Bn * (float)Dn)));
    atomicAdd(losses + 1, so * (1.f / ((float)Bn * (float)Rn)));
  }
}

extern "C" void kernel_launch(void* const* d_in, const int* in_sizes, int n_in,
                              void* d_out, int out_size, void* d_ws, size_t ws_size,
                              hipStream_t stream) {
  const float* inputs    = (const float*)d_in[0];
  const float* omega_in  = (const float*)d_in[1];
  const float* gamma_in  = (const float*)d_in[2];
  const float* alpha_in  = (const float*)d_in[3];
  const float* W_proj    = (const float*)d_in[4];
  const float* b_proj    = (const float*)d_in[5];
  const float* omega_res = (const float*)d_in[6];
  const float* gamma_res = (const float*)d_in[7];
  const float* alpha_res = (const float*)d_in[8];
  const float* omega_out = (const float*)d_in[9];
  const float* gamma_out = (const float*)d_in[10];
  const float* alpha_out = (const float*)d_in[11];
  const float* W_read    = (const float*)d_in[12];
  const float* b_read    = (const float*)d_in[13];

  float* out = (float*)d_out;
  float* losses = out + (size_t)Bn * Sn * Dn;  // outputs: preds | pc_in | pc_out

  // ws layout: [Wp_b 512KB][Wr_b 512KB][partial preds 64MB (split mode)]
  bf16_t* Wp_b = (bf16_t*)d_ws;
  bf16_t* Wr_b = Wp_b + (size_t)Rn * Dn;
  float* part = (float*)(Wr_b + (size_t)Rn * Dn);

  const size_t need = 2u * Rn * Dn * sizeof(bf16_t) +
                      (size_t)Bn * Sn * Dn * sizeof(float);
  const bool split = ws_size >= need;

  k_prep<<<1024, 256, 0, stream>>>(W_proj, W_read, Wp_b, Wr_b, losses);
  if (split) {
    k_fused<1><<<Bn * 2, 512, 0, stream>>>(inputs, omega_in, gamma_in, alpha_in,
                                           Wp_b, b_proj,
                                           omega_res, gamma_res, alpha_res,
                                           omega_out, gamma_out, alpha_out,
                                           Wr_b, out, part, losses);
    k_combine<<<(Bn * Sn * Dn / 4) / 256, 256, 0, stream>>>(out, part, b_read);
  } else {
    k_zero<<<(Bn * Sn * Dn / 4) / 256, 256, 0, stream>>>(out, b_read);
    k_fused<0><<<Bn * 2, 512, 0, stream>>>(inputs, omega_in, gamma_in, alpha_in,
                                           Wp_b, b_proj,
                                           omega_res, gamma_res, alpha_res,
                                           omega_out, gamma_out, alpha_out,
                                           Wr_b, out, part, losses);
  }
}